// Round 10
// baseline (603.252 us; speedup 1.0000x reference)
//
#include <hip/hip_runtime.h>

#define DHC 128
#define BSHIFT 8
#define BSIZE 256  // dst nodes per bucket

typedef __attribute__((ext_vector_type(8))) __bf16 bf16x8;
typedef __attribute__((ext_vector_type(8))) unsigned short ushort8;
typedef __attribute__((ext_vector_type(4))) float floatx4;

__device__ inline unsigned short f2bf(float f) {
    unsigned int u = __float_as_uint(f);
    return (unsigned short)((u + 0x7FFFu + ((u >> 16) & 1u)) >> 16);
}
__device__ inline float bf2f_lo(unsigned int v) { return __uint_as_float(v << 16); }
__device__ inline float bf2f_hi(unsigned int v) { return __uint_as_float(v & 0xFFFF0000u); }

// ---------------- graph prep: bucket sort by dst>>8, then per-bucket CSR ----------------

__global__ __launch_bounds__(256) void bucket_hist(const int* __restrict__ dst,
                                                   int* __restrict__ bcount, int e) {
    __shared__ int h[512];
    for (int i = threadIdx.x; i < 512; i += 256) h[i] = 0;
    __syncthreads();
    int base = blockIdx.x * 4096 + threadIdx.x;
#pragma unroll
    for (int j = 0; j < 16; j++) {
        int i = base + j * 256;
        if (i < e) atomicAdd(&h[dst[i] >> BSHIFT], 1);
    }
    __syncthreads();
    for (int i = threadIdx.x; i < 512; i += 256)
        if (h[i]) atomicAdd(&bcount[i], h[i]);
}

__global__ void bucket_scan(const int* __restrict__ bcount, int* __restrict__ bbase,
                            int* __restrict__ bcur, int* __restrict__ row_ptr,
                            int nb, int n, int e) {
    __shared__ int s[512];
    int t = threadIdx.x;
    s[t] = (t < nb) ? bcount[t] : 0;
    __syncthreads();
    for (int off = 1; off < 512; off <<= 1) {
        int add = (t >= off) ? s[t - off] : 0;
        __syncthreads();
        s[t] += add;
        __syncthreads();
    }
    if (t < nb) {
        int ex = (t == 0) ? 0 : s[t - 1];
        bbase[t] = ex;
        bcur[t] = ex;
    }
    if (t == 0) {
        bbase[nb] = e;
        row_ptr[n] = e;
    }
}

// scatter edges into bucket regions; packed entry = src | (dst_local << 20)
__global__ __launch_bounds__(256) void bucket_scatter(const int* __restrict__ src,
                                                      const int* __restrict__ dst,
                                                      int* __restrict__ bcur,
                                                      unsigned int* __restrict__ ebuf, int e) {
    __shared__ int h[512];
    __shared__ int rsv[512];
    for (int i = threadIdx.x; i < 512; i += 256) h[i] = 0;
    __syncthreads();
    int base = blockIdx.x * 4096 + threadIdx.x;
    int sreg[16], dreg[16];
#pragma unroll
    for (int j = 0; j < 16; j++) {
        int i = base + j * 256;
        if (i < e) {
            sreg[j] = src[i];
            dreg[j] = dst[i];
            atomicAdd(&h[dreg[j] >> BSHIFT], 1);
        } else {
            dreg[j] = -1;
        }
    }
    __syncthreads();
    for (int i = threadIdx.x; i < 512; i += 256) {
        int c = h[i];
        rsv[i] = c ? atomicAdd(&bcur[i], c) : 0;
        h[i] = 0;
    }
    __syncthreads();
#pragma unroll
    for (int j = 0; j < 16; j++) {
        if (dreg[j] >= 0) {
            int b = dreg[j] >> BSHIFT;
            int pos = rsv[b] + atomicAdd(&h[b], 1);
            ebuf[pos] = (unsigned int)sreg[j] | ((unsigned int)(dreg[j] & (BSIZE - 1)) << 20);
        }
    }
}

// one block per bucket: local deg, local scan -> row_ptr, dinv, csr_src
__global__ __launch_bounds__(256) void bucket_build(const unsigned int* __restrict__ ebuf,
                                                    const int* __restrict__ bbase,
                                                    int* __restrict__ row_ptr,
                                                    int* __restrict__ csr_src,
                                                    float* __restrict__ dinv, int n) {
    __shared__ int ldeg[256];
    __shared__ int lcur[256];
    int b = blockIdx.x;
    int t = threadIdx.x;
    int beg = bbase[b], end = bbase[b + 1];
    ldeg[t] = 0;
    __syncthreads();
    for (int i = beg + t; i < end; i += 256) atomicAdd(&ldeg[ebuf[i] >> 20], 1);
    __syncthreads();
    int deg = ldeg[t];
    lcur[t] = deg;
    __syncthreads();
    for (int off = 1; off < 256; off <<= 1) {
        int add = (t >= off) ? lcur[t - off] : 0;
        __syncthreads();
        lcur[t] += add;
        __syncthreads();
    }
    int rp = beg + lcur[t] - deg;  // exclusive
    int node = (b << BSHIFT) + t;
    if (node < n) {
        row_ptr[node] = rp;
        dinv[node] = rsqrtf((float)(deg + 1));
    }
    __syncthreads();
    lcur[t] = rp;
    __syncthreads();
    for (int i = beg + t; i < end; i += 256) {
        unsigned int p = ebuf[i];
        int pos = atomicAdd(&lcur[p >> 20], 1);
        csr_src[pos] = (int)(p & 0xFFFFFu);
    }
}

// ---------------- weight convert: 3x W[128k][128n] fp32 -> WT[n][k] bf16 ----------------
__global__ void wconv3_k(const float* __restrict__ W1, const float* __restrict__ W2,
                         const float* __restrict__ W3, unsigned short* __restrict__ WTall) {
    int idx = blockIdx.x * 256 + threadIdx.x;  // 3*16384
    int wsel = idx >> 14;
    int i = idx & 16383;
    int nn = i >> 7, k = i & 127;
    const float* W = (wsel == 0) ? W1 : (wsel == 1) ? W2 : W3;
    WTall[idx] = f2bf(W[k * 128 + nn]);
}

// ---------------- MFMA bf16 GEMM: out = A[N,128] @ W, B staged in LDS ----------------
template <int MODE, int AF32>
__global__ __launch_bounds__(256, 4) void gemm_k(const void* __restrict__ Avoid,
                                                 const unsigned short* __restrict__ WT,
                                                 const float* __restrict__ bias,
                                                 unsigned short* __restrict__ outB,
                                                 float* __restrict__ outF,
                                                 const float* __restrict__ Wr,
                                                 const float* __restrict__ br, int n) {
    __shared__ unsigned short Ws[32 * 512];
    {
        for (int c = threadIdx.x; c < 2048; c += 256) {
            int f = c >> 6;
            int l = c & 63;
            int ks = f >> 3, ct = f & 7;
            int nn = ct * 16 + (l & 15);
            int kb = ks * 32 + (l >> 4) * 8;
            *(uint4*)(&Ws[c * 8]) = *(const uint4*)(&WT[nn * 128 + kb]);
        }
    }
    __syncthreads();
    const int wave = threadIdx.x >> 6;
    const int lane = threadIdx.x & 63;
    const int rowbase = blockIdx.x * 128 + wave * 32;
    const int m = lane & 15;
    const int kq = lane >> 4;  // 0..3

    floatx4 acc[2][8];
#pragma unroll
    for (int rt = 0; rt < 2; rt++)
#pragma unroll
        for (int ct = 0; ct < 8; ct++) acc[rt][ct] = (floatx4){0.f, 0.f, 0.f, 0.f};

    const int r0 = min(rowbase + m, n - 1);
    const int r1 = min(rowbase + 16 + m, n - 1);

#pragma unroll
    for (int ks = 0; ks < 4; ks++) {
        const int kb = ks * 32 + kq * 8;
        bf16x8 a0, a1;
        if (AF32) {
            const float* Af = (const float*)Avoid;
            float4 f00 = *(const float4*)(Af + (size_t)r0 * 128 + kb);
            float4 f01 = *(const float4*)(Af + (size_t)r0 * 128 + kb + 4);
            float4 f10 = *(const float4*)(Af + (size_t)r1 * 128 + kb);
            float4 f11 = *(const float4*)(Af + (size_t)r1 * 128 + kb + 4);
            ushort8 u0, u1;
            u0[0] = f2bf(f00.x); u0[1] = f2bf(f00.y); u0[2] = f2bf(f00.z); u0[3] = f2bf(f00.w);
            u0[4] = f2bf(f01.x); u0[5] = f2bf(f01.y); u0[6] = f2bf(f01.z); u0[7] = f2bf(f01.w);
            u1[0] = f2bf(f10.x); u1[1] = f2bf(f10.y); u1[2] = f2bf(f10.z); u1[3] = f2bf(f10.w);
            u1[4] = f2bf(f11.x); u1[5] = f2bf(f11.y); u1[6] = f2bf(f11.z); u1[7] = f2bf(f11.w);
            a0 = __builtin_bit_cast(bf16x8, u0);
            a1 = __builtin_bit_cast(bf16x8, u1);
        } else {
            const unsigned short* Ab = (const unsigned short*)Avoid;
            a0 = __builtin_bit_cast(bf16x8, *(const ushort8*)(Ab + (size_t)r0 * 128 + kb));
            a1 = __builtin_bit_cast(bf16x8, *(const ushort8*)(Ab + (size_t)r1 * 128 + kb));
        }
#pragma unroll
        for (int ct = 0; ct < 8; ct++) {
            bf16x8 bfr = __builtin_bit_cast(bf16x8,
                *(const ushort8*)(&Ws[(ks * 8 + ct) * 512 + lane * 8]));
            acc[0][ct] = __builtin_amdgcn_mfma_f32_16x16x32_bf16(a0, bfr, acc[0][ct], 0, 0, 0);
            acc[1][ct] = __builtin_amdgcn_mfma_f32_16x16x32_bf16(a1, bfr, acc[1][ct], 0, 0, 0);
        }
    }

    if (MODE == 0) {
#pragma unroll
        for (int rt = 0; rt < 2; rt++) {
#pragma unroll
            for (int ct = 0; ct < 8; ct++) {
                int col = ct * 16 + m;
#pragma unroll
                for (int i = 0; i < 4; i++) {
                    int r = rowbase + rt * 16 + kq * 4 + i;
                    if (r < n) outB[(size_t)r * 128 + col] = f2bf(acc[rt][ct][i]);
                }
            }
        }
    } else {
        float bcv[8], wr0[8], wr1[8];
#pragma unroll
        for (int ct = 0; ct < 8; ct++) {
            int col = ct * 16 + m;
            bcv[ct] = bias[col];
            float2 wv = ((const float2*)Wr)[col];
            wr0[ct] = wv.x;
            wr1[ct] = wv.y;
        }
        float br0 = br[0], br1 = br[1];
#pragma unroll
        for (int rt = 0; rt < 2; rt++) {
#pragma unroll
            for (int i = 0; i < 4; i++) {
                float p0 = 0.f, p1 = 0.f;
#pragma unroll
                for (int ct = 0; ct < 8; ct++) {
                    float v = fmaxf(acc[rt][ct][i] + bcv[ct], 0.f);
                    p0 = fmaf(v, wr0[ct], p0);
                    p1 = fmaf(v, wr1[ct], p1);
                }
#pragma unroll
                for (int mk = 1; mk < 16; mk <<= 1) {
                    p0 += __shfl_xor(p0, mk);
                    p1 += __shfl_xor(p1, mk);
                }
                int r = rowbase + rt * 16 + kq * 4 + i;
                if (m == 0 && r < n) ((float2*)outF)[r] = make_float2(p0 + br0, p1 + br1);
            }
        }
    }
}

// ---------------- CSR gather aggregation: 16 lanes/node, natural order, 8-edge unroll ----------------
// STATS=1: also accumulate per-channel sum/sumsq of fp32 outputs (BN batch stats).
template <int STATS>
__global__ __launch_bounds__(256) void agg_k(const unsigned short* __restrict__ hW,
                                             const int* __restrict__ csr,
                                             const int* __restrict__ row_ptr,
                                             const float* __restrict__ dinv,
                                             const float* __restrict__ bias,
                                             unsigned short* __restrict__ out,
                                             float* __restrict__ gsum,
                                             float* __restrict__ gsumsq, int n) {
    int node = blockIdx.x * 16 + (threadIdx.x >> 4);
    int t = threadIdx.x & 15;
    bool valid = node < n;
    int beg = 0, end = 0;
    float dd = 0.f;
    if (valid) {
        beg = row_ptr[node];
        end = row_ptr[node + 1];
        dd = dinv[node];
    }
    const uint4* h4 = (const uint4*)hW;
    float a[8];
#pragma unroll
    for (int i = 0; i < 8; i++) a[i] = 0.f;

    int e = beg;
    for (; e + 7 < end; e += 8) {
        int s[8];
#pragma unroll
        for (int k = 0; k < 8; k++) s[k] = csr[e + k];
        float c[8];
#pragma unroll
        for (int k = 0; k < 8; k++) c[k] = dinv[s[k]] * dd;
        uint4 v[8];
#pragma unroll
        for (int k = 0; k < 8; k++) v[k] = h4[(size_t)s[k] * 16 + t];
#pragma unroll
        for (int k = 0; k < 8; k++) {
            a[0] = fmaf(c[k], bf2f_lo(v[k].x), a[0]);
            a[1] = fmaf(c[k], bf2f_hi(v[k].x), a[1]);
            a[2] = fmaf(c[k], bf2f_lo(v[k].y), a[2]);
            a[3] = fmaf(c[k], bf2f_hi(v[k].y), a[3]);
            a[4] = fmaf(c[k], bf2f_lo(v[k].z), a[4]);
            a[5] = fmaf(c[k], bf2f_hi(v[k].z), a[5]);
            a[6] = fmaf(c[k], bf2f_lo(v[k].w), a[6]);
            a[7] = fmaf(c[k], bf2f_hi(v[k].w), a[7]);
        }
    }
    for (; e < end; e++) {
        int s = csr[e];
        float c = dinv[s] * dd;
        uint4 v = h4[(size_t)s * 16 + t];
        a[0] = fmaf(c, bf2f_lo(v.x), a[0]); a[1] = fmaf(c, bf2f_hi(v.x), a[1]);
        a[2] = fmaf(c, bf2f_lo(v.y), a[2]); a[3] = fmaf(c, bf2f_hi(v.y), a[3]);
        a[4] = fmaf(c, bf2f_lo(v.z), a[4]); a[5] = fmaf(c, bf2f_hi(v.z), a[5]);
        a[6] = fmaf(c, bf2f_lo(v.w), a[6]); a[7] = fmaf(c, bf2f_hi(v.w), a[7]);
    }

    if (valid) {  // self-loop: coef = dinv^2
        float sc = dd * dd;
        uint4 v = h4[(size_t)node * 16 + t];
        a[0] = fmaf(sc, bf2f_lo(v.x), a[0]); a[1] = fmaf(sc, bf2f_hi(v.x), a[1]);
        a[2] = fmaf(sc, bf2f_lo(v.y), a[2]); a[3] = fmaf(sc, bf2f_hi(v.y), a[3]);
        a[4] = fmaf(sc, bf2f_lo(v.z), a[4]); a[5] = fmaf(sc, bf2f_hi(v.z), a[5]);
        a[6] = fmaf(sc, bf2f_lo(v.w), a[6]); a[7] = fmaf(sc, bf2f_hi(v.w), a[7]);
    }

    float4 b0 = ((const float4*)bias)[t * 2];
    float4 b1 = ((const float4*)bias)[t * 2 + 1];
    float r[8];
    r[0] = fmaxf(a[0] + b0.x, 0.f); r[1] = fmaxf(a[1] + b0.y, 0.f);
    r[2] = fmaxf(a[2] + b0.z, 0.f); r[3] = fmaxf(a[3] + b0.w, 0.f);
    r[4] = fmaxf(a[4] + b1.x, 0.f); r[5] = fmaxf(a[5] + b1.y, 0.f);
    r[6] = fmaxf(a[6] + b1.z, 0.f); r[7] = fmaxf(a[7] + b1.w, 0.f);

    if (valid) {
        uint4 o;
        o.x = (unsigned int)f2bf(r[0]) | ((unsigned int)f2bf(r[1]) << 16);
        o.y = (unsigned int)f2bf(r[2]) | ((unsigned int)f2bf(r[3]) << 16);
        o.z = (unsigned int)f2bf(r[4]) | ((unsigned int)f2bf(r[5]) << 16);
        o.w = (unsigned int)f2bf(r[6]) | ((unsigned int)f2bf(r[7]) << 16);
        ((uint4*)out)[(size_t)node * 16 + t] = o;
    }

    if (STATS) {
        __shared__ float ssum[128], ssq[128];
        if (threadIdx.x < 128) {
            ssum[threadIdx.x] = 0.f;
            ssq[threadIdx.x] = 0.f;
        }
        __syncthreads();
#pragma unroll
        for (int i = 0; i < 8; i++) {
            float sv = valid ? r[i] : 0.f;
            float sq = sv * sv;
            sv += __shfl_xor(sv, 16); sq += __shfl_xor(sq, 16);
            sv += __shfl_xor(sv, 32); sq += __shfl_xor(sq, 32);
            if ((threadIdx.x & 63) < 16) {  // group 0 of each wave
                atomicAdd(&ssum[t * 8 + i], sv);
                atomicAdd(&ssq[t * 8 + i], sq);
            }
        }
        __syncthreads();
        if (threadIdx.x < 128) {
            atomicAdd(&gsum[threadIdx.x], ssum[threadIdx.x]);
            atomicAdd(&gsumsq[threadIdx.x], ssq[threadIdx.x]);
        }
    }
}

// ---------------- BN finalize: scale/shift from stats; init bcP ----------------
__global__ void bn_finalize(const float* __restrict__ gsum, const float* __restrict__ gsumsq,
                            const float* __restrict__ gamma, const float* __restrict__ beta,
                            const float* __restrict__ bc, float* __restrict__ scale,
                            float* __restrict__ shift, float* __restrict__ bcP, float invN) {
    int j = threadIdx.x;  // 128
    float mu = gsum[j] * invN;
    float var = gsumsq[j] * invN - mu * mu;
    float sc = gamma[j] * rsqrtf(var + 1e-5f);
    scale[j] = sc;
    shift[j] = beta[j] - mu * sc;
    bcP[j] = bc[j];
}

// ---------------- fold BN into Wc (parallel): WcT[j][k] = bf16(scale_k*Wc[k][j]); bcP += shift@Wc ----------------
__global__ __launch_bounds__(256) void wcfold(const float* __restrict__ Wc,
                                              const float* __restrict__ scale,
                                              const float* __restrict__ shift,
                                              unsigned short* __restrict__ WcT,
                                              float* __restrict__ bcP) {
    __shared__ float scS[128], shS[128];
    if (threadIdx.x < 128) {
        scS[threadIdx.x] = scale[threadIdx.x];
        shS[threadIdx.x] = shift[threadIdx.x];
    }
    __syncthreads();
    int idx = blockIdx.x * 256 + threadIdx.x;  // 16384; j inner -> coalesced Wc reads
    int j = idx & 127, k = idx >> 7;
    float w = Wc[k * 128 + j];
    WcT[j * 128 + k] = f2bf(scS[k] * w);
    atomicAdd(&bcP[j], shS[k] * w);
}

// ---------------- host ----------------

extern "C" void kernel_launch(void* const* d_in, const int* in_sizes, int n_in,
                              void* d_out, int out_size, void* d_ws, size_t ws_size,
                              hipStream_t stream) {
    const float* x = (const float*)d_in[0];
    const int* ei = (const int*)d_in[1];
    const float* W1 = (const float*)d_in[2];
    const float* b1 = (const float*)d_in[3];
    const float* W2 = (const float*)d_in[4];
    const float* b2 = (const float*)d_in[5];
    const float* W3 = (const float*)d_in[6];
    const float* b3 = (const float*)d_in[7];
    const float* gamma = (const float*)d_in[8];
    const float* beta = (const float*)d_in[9];
    const float* Wc = (const float*)d_in[10];
    const float* bc = (const float*)d_in[11];
    const float* Wr = (const float*)d_in[12];
    const float* br = (const float*)d_in[13];
    float* out = (float*)d_out;

    const int N = in_sizes[0] / DHC;
    const int E = in_sizes[1] / 2;
    const int* srcIdx = ei;
    const int* dstIdx = ei + E;
    const int NB = (N + BSIZE - 1) >> BSHIFT;

    char* w = (char*)d_ws;
    size_t off = 0;
    auto alloc = [&](size_t bytes) -> void* {
        void* p = w + off;
        off += (bytes + 255) & ~(size_t)255;
        return p;
    };
    unsigned short* bufA = (unsigned short*)alloc((size_t)N * DHC * 2);
    unsigned short* bufB = (unsigned short*)alloc((size_t)N * DHC * 2);
    unsigned int* ebuf = (unsigned int*)alloc((size_t)E * 4);
    int* csr_src = (int*)alloc((size_t)E * 4);
    int* row_ptr = (int*)alloc((size_t)(N + 1) * 4);
    float* dinv = (float*)alloc((size_t)N * 4);
    // zeroed region: bcount[512] ++ stats[256] — one memset
    int* bcount = (int*)alloc(512 * 4 + 256 * 4);
    float* stats = (float*)(bcount + 512);
    float* gsum = stats;
    float* gsumsq = stats + 128;
    int* bbase = (int*)alloc(512 * 4);
    int* bcur = (int*)alloc(512 * 4);
    unsigned short* WTall = (unsigned short*)alloc((size_t)3 * 16384 * 2);
    unsigned short* WT1 = WTall;
    unsigned short* WT2 = WTall + 16384;
    unsigned short* WT3 = WTall + 32768;
    unsigned short* WcT = (unsigned short*)alloc(16384 * 2);
    float* scale = (float*)alloc(128 * 4);
    float* shift = (float*)alloc(128 * 4);
    float* bcP = (float*)alloc(128 * 4);
    (void)ws_size; (void)n_in; (void)out_size;

    hipMemsetAsync(bcount, 0, 512 * 4 + 256 * 4, stream);

    const int EB = (E + 4095) / 4096;
    bucket_hist<<<EB, 256, 0, stream>>>(dstIdx, bcount, E);
    bucket_scan<<<1, 512, 0, stream>>>(bcount, bbase, bcur, row_ptr, NB, N, E);
    bucket_scatter<<<EB, 256, 0, stream>>>(srcIdx, dstIdx, bcur, ebuf, E);
    bucket_build<<<NB, 256, 0, stream>>>(ebuf, bbase, row_ptr, csr_src, dinv, N);

    wconv3_k<<<192, 256, 0, stream>>>(W1, W2, W3, WTall);

    const int gemmBlocks = (N + 127) / 128;
    const int aggBlocks = (N + 15) / 16;

    // layer 1 (A = x fp32, converted in-flight)
    gemm_k<0, 1><<<gemmBlocks, 256, 0, stream>>>(x, WT1, nullptr, bufB, nullptr, nullptr, nullptr, N);
    agg_k<0><<<aggBlocks, 256, 0, stream>>>(bufB, csr_src, row_ptr, dinv, b1, bufA, nullptr, nullptr, N);
    // layer 2
    gemm_k<0, 0><<<gemmBlocks, 256, 0, stream>>>(bufA, WT2, nullptr, bufB, nullptr, nullptr, nullptr, N);
    agg_k<0><<<aggBlocks, 256, 0, stream>>>(bufB, csr_src, row_ptr, dinv, b2, bufA, nullptr, nullptr, N);
    // layer 3 (+ fused BN stats)
    gemm_k<0, 0><<<gemmBlocks, 256, 0, stream>>>(bufA, WT3, nullptr, bufB, nullptr, nullptr, nullptr, N);
    agg_k<1><<<aggBlocks, 256, 0, stream>>>(bufB, csr_src, row_ptr, dinv, b3, bufA, gsum, gsumsq, N);

    // BN fold + classifier GEMM fused with output projection
    bn_finalize<<<1, 128, 0, stream>>>(gsum, gsumsq, gamma, beta, bc, scale, shift, bcP, 1.0f / (float)N);
    wcfold<<<64, 256, 0, stream>>>(Wc, scale, shift, WcT, bcP);
    gemm_k<2, 0><<<gemmBlocks, 256, 0, stream>>>(bufA, WcT, bcP, nullptr, out, Wr, br, N);
}

// Round 12
// 541.040 us; speedup vs baseline: 1.1150x; 1.1150x over previous
//
#include <hip/hip_runtime.h>

#define DHC 128
#define BSHIFT 8
#define BSIZE 256  // dst nodes per bucket

typedef __attribute__((ext_vector_type(8))) __bf16 bf16x8;
typedef __attribute__((ext_vector_type(8))) unsigned short ushort8;
typedef __attribute__((ext_vector_type(4))) float floatx4;

__device__ inline unsigned short f2bf(float f) {
    unsigned int u = __float_as_uint(f);
    return (unsigned short)((u + 0x7FFFu + ((u >> 16) & 1u)) >> 16);
}
__device__ inline float bf2f_lo(unsigned int v) { return __uint_as_float(v << 16); }
__device__ inline float bf2f_hi(unsigned int v) { return __uint_as_float(v & 0xFFFF0000u); }

// ---------------- graph prep: bucket sort by dst>>8, then per-bucket CSR ----------------

__global__ __launch_bounds__(256) void bucket_hist(const int* __restrict__ dst,
                                                   int* __restrict__ bcount, int e) {
    __shared__ int h[512];
    for (int i = threadIdx.x; i < 512; i += 256) h[i] = 0;
    __syncthreads();
    int base = blockIdx.x * 4096 + threadIdx.x;
#pragma unroll
    for (int j = 0; j < 16; j++) {
        int i = base + j * 256;
        if (i < e) atomicAdd(&h[dst[i] >> BSHIFT], 1);
    }
    __syncthreads();
    for (int i = threadIdx.x; i < 512; i += 256)
        if (h[i]) atomicAdd(&bcount[i], h[i]);
}

__global__ void bucket_scan(const int* __restrict__ bcount, int* __restrict__ bbase,
                            int* __restrict__ bcur, int* __restrict__ row_ptr,
                            int nb, int n, int e) {
    __shared__ int s[512];
    int t = threadIdx.x;
    s[t] = (t < nb) ? bcount[t] : 0;
    __syncthreads();
    for (int off = 1; off < 512; off <<= 1) {
        int add = (t >= off) ? s[t - off] : 0;
        __syncthreads();
        s[t] += add;
        __syncthreads();
    }
    if (t < nb) {
        int ex = (t == 0) ? 0 : s[t - 1];
        bbase[t] = ex;
        bcur[t] = ex;
    }
    if (t == 0) {
        bbase[nb] = e;
        row_ptr[n] = e;
    }
}

// scatter edges into bucket regions; packed entry = src | (dst_local << 20)
__global__ __launch_bounds__(256) void bucket_scatter(const int* __restrict__ src,
                                                      const int* __restrict__ dst,
                                                      int* __restrict__ bcur,
                                                      unsigned int* __restrict__ ebuf, int e) {
    __shared__ int h[512];
    __shared__ int rsv[512];
    for (int i = threadIdx.x; i < 512; i += 256) h[i] = 0;
    __syncthreads();
    int base = blockIdx.x * 4096 + threadIdx.x;
    int sreg[16], dreg[16];
#pragma unroll
    for (int j = 0; j < 16; j++) {
        int i = base + j * 256;
        if (i < e) {
            sreg[j] = src[i];
            dreg[j] = dst[i];
            atomicAdd(&h[dreg[j] >> BSHIFT], 1);
        } else {
            dreg[j] = -1;
        }
    }
    __syncthreads();
    for (int i = threadIdx.x; i < 512; i += 256) {
        int c = h[i];
        rsv[i] = c ? atomicAdd(&bcur[i], c) : 0;
        h[i] = 0;
    }
    __syncthreads();
#pragma unroll
    for (int j = 0; j < 16; j++) {
        if (dreg[j] >= 0) {
            int b = dreg[j] >> BSHIFT;
            int pos = rsv[b] + atomicAdd(&h[b], 1);
            ebuf[pos] = (unsigned int)sreg[j] | ((unsigned int)(dreg[j] & (BSIZE - 1)) << 20);
        }
    }
}

// one block per bucket: local deg, local scan -> row_ptr, dinv, csr_src
__global__ __launch_bounds__(256) void bucket_build(const unsigned int* __restrict__ ebuf,
                                                    const int* __restrict__ bbase,
                                                    int* __restrict__ row_ptr,
                                                    int* __restrict__ csr_src,
                                                    float* __restrict__ dinv, int n) {
    __shared__ int ldeg[256];
    __shared__ int lcur[256];
    int b = blockIdx.x;
    int t = threadIdx.x;
    int beg = bbase[b], end = bbase[b + 1];
    ldeg[t] = 0;
    __syncthreads();
    for (int i = beg + t; i < end; i += 256) atomicAdd(&ldeg[ebuf[i] >> 20], 1);
    __syncthreads();
    int deg = ldeg[t];
    lcur[t] = deg;
    __syncthreads();
    for (int off = 1; off < 256; off <<= 1) {
        int add = (t >= off) ? lcur[t - off] : 0;
        __syncthreads();
        lcur[t] += add;
        __syncthreads();
    }
    int rp = beg + lcur[t] - deg;  // exclusive
    int node = (b << BSHIFT) + t;
    if (node < n) {
        row_ptr[node] = rp;
        dinv[node] = rsqrtf((float)(deg + 1));
    }
    __syncthreads();
    lcur[t] = rp;
    __syncthreads();
    for (int i = beg + t; i < end; i += 256) {
        unsigned int p = ebuf[i];
        int pos = atomicAdd(&lcur[p >> 20], 1);
        csr_src[pos] = (int)(p & 0xFFFFFu);
    }
}

// ---------------- weight convert: 3x W[128k][128n] fp32 -> WT[n][k] bf16 ----------------
__global__ void wconv3_k(const float* __restrict__ W1, const float* __restrict__ W2,
                         const float* __restrict__ W3, unsigned short* __restrict__ WTall) {
    int idx = blockIdx.x * 256 + threadIdx.x;  // 3*16384
    int wsel = idx >> 14;
    int i = idx & 16383;
    int nn = i >> 7, k = i & 127;
    const float* W = (wsel == 0) ? W1 : (wsel == 1) ? W2 : W3;
    WTall[idx] = f2bf(W[k * 128 + nn]);
}

// ---------------- MFMA bf16 GEMM: out = A[N,128] @ W, B staged in LDS ----------------
template <int MODE, int AF32>
__global__ __launch_bounds__(256, 4) void gemm_k(const void* __restrict__ Avoid,
                                                 const unsigned short* __restrict__ WT,
                                                 const float* __restrict__ bias,
                                                 unsigned short* __restrict__ outB,
                                                 float* __restrict__ outF,
                                                 const float* __restrict__ Wr,
                                                 const float* __restrict__ br, int n) {
    __shared__ unsigned short Ws[32 * 512];
    {
        for (int c = threadIdx.x; c < 2048; c += 256) {
            int f = c >> 6;
            int l = c & 63;
            int ks = f >> 3, ct = f & 7;
            int nn = ct * 16 + (l & 15);
            int kb = ks * 32 + (l >> 4) * 8;
            *(uint4*)(&Ws[c * 8]) = *(const uint4*)(&WT[nn * 128 + kb]);
        }
    }
    __syncthreads();
    const int wave = threadIdx.x >> 6;
    const int lane = threadIdx.x & 63;
    const int rowbase = blockIdx.x * 128 + wave * 32;
    const int m = lane & 15;
    const int kq = lane >> 4;  // 0..3

    floatx4 acc[2][8];
#pragma unroll
    for (int rt = 0; rt < 2; rt++)
#pragma unroll
        for (int ct = 0; ct < 8; ct++) acc[rt][ct] = (floatx4){0.f, 0.f, 0.f, 0.f};

    const int r0 = min(rowbase + m, n - 1);
    const int r1 = min(rowbase + 16 + m, n - 1);

#pragma unroll
    for (int ks = 0; ks < 4; ks++) {
        const int kb = ks * 32 + kq * 8;
        bf16x8 a0, a1;
        if (AF32) {
            const float* Af = (const float*)Avoid;
            float4 f00 = *(const float4*)(Af + (size_t)r0 * 128 + kb);
            float4 f01 = *(const float4*)(Af + (size_t)r0 * 128 + kb + 4);
            float4 f10 = *(const float4*)(Af + (size_t)r1 * 128 + kb);
            float4 f11 = *(const float4*)(Af + (size_t)r1 * 128 + kb + 4);
            ushort8 u0, u1;
            u0[0] = f2bf(f00.x); u0[1] = f2bf(f00.y); u0[2] = f2bf(f00.z); u0[3] = f2bf(f00.w);
            u0[4] = f2bf(f01.x); u0[5] = f2bf(f01.y); u0[6] = f2bf(f01.z); u0[7] = f2bf(f01.w);
            u1[0] = f2bf(f10.x); u1[1] = f2bf(f10.y); u1[2] = f2bf(f10.z); u1[3] = f2bf(f10.w);
            u1[4] = f2bf(f11.x); u1[5] = f2bf(f11.y); u1[6] = f2bf(f11.z); u1[7] = f2bf(f11.w);
            a0 = __builtin_bit_cast(bf16x8, u0);
            a1 = __builtin_bit_cast(bf16x8, u1);
        } else {
            const unsigned short* Ab = (const unsigned short*)Avoid;
            a0 = __builtin_bit_cast(bf16x8, *(const ushort8*)(Ab + (size_t)r0 * 128 + kb));
            a1 = __builtin_bit_cast(bf16x8, *(const ushort8*)(Ab + (size_t)r1 * 128 + kb));
        }
#pragma unroll
        for (int ct = 0; ct < 8; ct++) {
            bf16x8 bfr = __builtin_bit_cast(bf16x8,
                *(const ushort8*)(&Ws[(ks * 8 + ct) * 512 + lane * 8]));
            acc[0][ct] = __builtin_amdgcn_mfma_f32_16x16x32_bf16(a0, bfr, acc[0][ct], 0, 0, 0);
            acc[1][ct] = __builtin_amdgcn_mfma_f32_16x16x32_bf16(a1, bfr, acc[1][ct], 0, 0, 0);
        }
    }

    if (MODE == 0) {
#pragma unroll
        for (int rt = 0; rt < 2; rt++) {
#pragma unroll
            for (int ct = 0; ct < 8; ct++) {
                int col = ct * 16 + m;
#pragma unroll
                for (int i = 0; i < 4; i++) {
                    int r = rowbase + rt * 16 + kq * 4 + i;
                    if (r < n) outB[(size_t)r * 128 + col] = f2bf(acc[rt][ct][i]);
                }
            }
        }
    } else {
        float bcv[8], wr0[8], wr1[8];
#pragma unroll
        for (int ct = 0; ct < 8; ct++) {
            int col = ct * 16 + m;
            bcv[ct] = bias[col];
            float2 wv = ((const float2*)Wr)[col];
            wr0[ct] = wv.x;
            wr1[ct] = wv.y;
        }
        float br0 = br[0], br1 = br[1];
#pragma unroll
        for (int rt = 0; rt < 2; rt++) {
#pragma unroll
            for (int i = 0; i < 4; i++) {
                float p0 = 0.f, p1 = 0.f;
#pragma unroll
                for (int ct = 0; ct < 8; ct++) {
                    float v = fmaxf(acc[rt][ct][i] + bcv[ct], 0.f);
                    p0 = fmaf(v, wr0[ct], p0);
                    p1 = fmaf(v, wr1[ct], p1);
                }
#pragma unroll
                for (int mk = 1; mk < 16; mk <<= 1) {
                    p0 += __shfl_xor(p0, mk);
                    p1 += __shfl_xor(p1, mk);
                }
                int r = rowbase + rt * 16 + kq * 4 + i;
                if (m == 0 && r < n) ((float2*)outF)[r] = make_float2(p0 + br0, p1 + br1);
            }
        }
    }
}

// ---------------- CSR gather aggregation: 16 lanes/node, explicit 4-edge unroll ----------------
// Round-7-proven inner body (explicit scalars keep gathers in flight; arrays spill).
__global__ __launch_bounds__(256) void agg_k(const unsigned short* __restrict__ hW,
                                             const int* __restrict__ csr,
                                             const int* __restrict__ row_ptr,
                                             const float* __restrict__ dinv,
                                             const float* __restrict__ bias,
                                             unsigned short* __restrict__ out, int n) {
    int node = blockIdx.x * 16 + (threadIdx.x >> 4);
    int t = threadIdx.x & 15;
    if (node >= n) return;
    int beg = row_ptr[node], end = row_ptr[node + 1];
    float dd = dinv[node];
    const uint4* h4 = (const uint4*)hW;
    float a[8];
#pragma unroll
    for (int i = 0; i < 8; i++) a[i] = 0.f;

    int e = beg;
    for (; e + 3 < end; e += 4) {
        int s0 = csr[e + 0], s1 = csr[e + 1], s2 = csr[e + 2], s3 = csr[e + 3];
        float c0 = dinv[s0] * dd, c1 = dinv[s1] * dd, c2 = dinv[s2] * dd, c3 = dinv[s3] * dd;
        uint4 v0 = h4[(size_t)s0 * 16 + t];
        uint4 v1 = h4[(size_t)s1 * 16 + t];
        uint4 v2 = h4[(size_t)s2 * 16 + t];
        uint4 v3 = h4[(size_t)s3 * 16 + t];
        a[0] = fmaf(c0, bf2f_lo(v0.x), a[0]); a[1] = fmaf(c0, bf2f_hi(v0.x), a[1]);
        a[2] = fmaf(c0, bf2f_lo(v0.y), a[2]); a[3] = fmaf(c0, bf2f_hi(v0.y), a[3]);
        a[4] = fmaf(c0, bf2f_lo(v0.z), a[4]); a[5] = fmaf(c0, bf2f_hi(v0.z), a[5]);
        a[6] = fmaf(c0, bf2f_lo(v0.w), a[6]); a[7] = fmaf(c0, bf2f_hi(v0.w), a[7]);
        a[0] = fmaf(c1, bf2f_lo(v1.x), a[0]); a[1] = fmaf(c1, bf2f_hi(v1.x), a[1]);
        a[2] = fmaf(c1, bf2f_lo(v1.y), a[2]); a[3] = fmaf(c1, bf2f_hi(v1.y), a[3]);
        a[4] = fmaf(c1, bf2f_lo(v1.z), a[4]); a[5] = fmaf(c1, bf2f_hi(v1.z), a[5]);
        a[6] = fmaf(c1, bf2f_lo(v1.w), a[6]); a[7] = fmaf(c1, bf2f_hi(v1.w), a[7]);
        a[0] = fmaf(c2, bf2f_lo(v2.x), a[0]); a[1] = fmaf(c2, bf2f_hi(v2.x), a[1]);
        a[2] = fmaf(c2, bf2f_lo(v2.y), a[2]); a[3] = fmaf(c2, bf2f_hi(v2.y), a[3]);
        a[4] = fmaf(c2, bf2f_lo(v2.z), a[4]); a[5] = fmaf(c2, bf2f_hi(v2.z), a[5]);
        a[6] = fmaf(c2, bf2f_lo(v2.w), a[6]); a[7] = fmaf(c2, bf2f_hi(v2.w), a[7]);
        a[0] = fmaf(c3, bf2f_lo(v3.x), a[0]); a[1] = fmaf(c3, bf2f_hi(v3.x), a[1]);
        a[2] = fmaf(c3, bf2f_lo(v3.y), a[2]); a[3] = fmaf(c3, bf2f_hi(v3.y), a[3]);
        a[4] = fmaf(c3, bf2f_lo(v3.z), a[4]); a[5] = fmaf(c3, bf2f_hi(v3.z), a[5]);
        a[6] = fmaf(c3, bf2f_lo(v3.w), a[6]); a[7] = fmaf(c3, bf2f_hi(v3.w), a[7]);
    }
    for (; e < end; e++) {
        int s = csr[e];
        float c = dinv[s] * dd;
        uint4 v = h4[(size_t)s * 16 + t];
        a[0] = fmaf(c, bf2f_lo(v.x), a[0]); a[1] = fmaf(c, bf2f_hi(v.x), a[1]);
        a[2] = fmaf(c, bf2f_lo(v.y), a[2]); a[3] = fmaf(c, bf2f_hi(v.y), a[3]);
        a[4] = fmaf(c, bf2f_lo(v.z), a[4]); a[5] = fmaf(c, bf2f_hi(v.z), a[5]);
        a[6] = fmaf(c, bf2f_lo(v.w), a[6]); a[7] = fmaf(c, bf2f_hi(v.w), a[7]);
    }

    // self-loop: coef = dinv^2
    {
        float sc = dd * dd;
        uint4 v = h4[(size_t)node * 16 + t];
        a[0] = fmaf(sc, bf2f_lo(v.x), a[0]); a[1] = fmaf(sc, bf2f_hi(v.x), a[1]);
        a[2] = fmaf(sc, bf2f_lo(v.y), a[2]); a[3] = fmaf(sc, bf2f_hi(v.y), a[3]);
        a[4] = fmaf(sc, bf2f_lo(v.z), a[4]); a[5] = fmaf(sc, bf2f_hi(v.z), a[5]);
        a[6] = fmaf(sc, bf2f_lo(v.w), a[6]); a[7] = fmaf(sc, bf2f_hi(v.w), a[7]);
    }
    float4 b0 = ((const float4*)bias)[t * 2];
    float4 b1 = ((const float4*)bias)[t * 2 + 1];
    uint4 o;
    o.x = (unsigned int)f2bf(fmaxf(a[0] + b0.x, 0.f)) |
          ((unsigned int)f2bf(fmaxf(a[1] + b0.y, 0.f)) << 16);
    o.y = (unsigned int)f2bf(fmaxf(a[2] + b0.z, 0.f)) |
          ((unsigned int)f2bf(fmaxf(a[3] + b0.w, 0.f)) << 16);
    o.z = (unsigned int)f2bf(fmaxf(a[4] + b1.x, 0.f)) |
          ((unsigned int)f2bf(fmaxf(a[5] + b1.y, 0.f)) << 16);
    o.w = (unsigned int)f2bf(fmaxf(a[6] + b1.z, 0.f)) |
          ((unsigned int)f2bf(fmaxf(a[7] + b1.w, 0.f)) << 16);
    ((uint4*)out)[(size_t)node * 16 + t] = o;
}

// ---------------- agg + fused BN batch stats (layer 3 only) ----------------
__global__ __launch_bounds__(256) void agg_stats_k(const unsigned short* __restrict__ hW,
                                                   const int* __restrict__ csr,
                                                   const int* __restrict__ row_ptr,
                                                   const float* __restrict__ dinv,
                                                   const float* __restrict__ bias,
                                                   unsigned short* __restrict__ out,
                                                   float* __restrict__ gsum,
                                                   float* __restrict__ gsumsq, int n) {
    __shared__ float ssum[128], ssq[128];
    int node = blockIdx.x * 16 + (threadIdx.x >> 4);
    int t = threadIdx.x & 15;
    bool valid = node < n;
    int beg = 0, end = 0;
    float dd = 0.f;
    if (valid) {
        beg = row_ptr[node];
        end = row_ptr[node + 1];
        dd = dinv[node];
    }
    const uint4* h4 = (const uint4*)hW;
    float a[8];
#pragma unroll
    for (int i = 0; i < 8; i++) a[i] = 0.f;

    int e = beg;
    for (; e + 3 < end; e += 4) {
        int s0 = csr[e + 0], s1 = csr[e + 1], s2 = csr[e + 2], s3 = csr[e + 3];
        float c0 = dinv[s0] * dd, c1 = dinv[s1] * dd, c2 = dinv[s2] * dd, c3 = dinv[s3] * dd;
        uint4 v0 = h4[(size_t)s0 * 16 + t];
        uint4 v1 = h4[(size_t)s1 * 16 + t];
        uint4 v2 = h4[(size_t)s2 * 16 + t];
        uint4 v3 = h4[(size_t)s3 * 16 + t];
        a[0] = fmaf(c0, bf2f_lo(v0.x), a[0]); a[1] = fmaf(c0, bf2f_hi(v0.x), a[1]);
        a[2] = fmaf(c0, bf2f_lo(v0.y), a[2]); a[3] = fmaf(c0, bf2f_hi(v0.y), a[3]);
        a[4] = fmaf(c0, bf2f_lo(v0.z), a[4]); a[5] = fmaf(c0, bf2f_hi(v0.z), a[5]);
        a[6] = fmaf(c0, bf2f_lo(v0.w), a[6]); a[7] = fmaf(c0, bf2f_hi(v0.w), a[7]);
        a[0] = fmaf(c1, bf2f_lo(v1.x), a[0]); a[1] = fmaf(c1, bf2f_hi(v1.x), a[1]);
        a[2] = fmaf(c1, bf2f_lo(v1.y), a[2]); a[3] = fmaf(c1, bf2f_hi(v1.y), a[3]);
        a[4] = fmaf(c1, bf2f_lo(v1.z), a[4]); a[5] = fmaf(c1, bf2f_hi(v1.z), a[5]);
        a[6] = fmaf(c1, bf2f_lo(v1.w), a[6]); a[7] = fmaf(c1, bf2f_hi(v1.w), a[7]);
        a[0] = fmaf(c2, bf2f_lo(v2.x), a[0]); a[1] = fmaf(c2, bf2f_hi(v2.x), a[1]);
        a[2] = fmaf(c2, bf2f_lo(v2.y), a[2]); a[3] = fmaf(c2, bf2f_hi(v2.y), a[3]);
        a[4] = fmaf(c2, bf2f_lo(v2.z), a[4]); a[5] = fmaf(c2, bf2f_hi(v2.z), a[5]);
        a[6] = fmaf(c2, bf2f_lo(v2.w), a[6]); a[7] = fmaf(c2, bf2f_hi(v2.w), a[7]);
        a[0] = fmaf(c3, bf2f_lo(v3.x), a[0]); a[1] = fmaf(c3, bf2f_hi(v3.x), a[1]);
        a[2] = fmaf(c3, bf2f_lo(v3.y), a[2]); a[3] = fmaf(c3, bf2f_hi(v3.y), a[3]);
        a[4] = fmaf(c3, bf2f_lo(v3.z), a[4]); a[5] = fmaf(c3, bf2f_hi(v3.z), a[5]);
        a[6] = fmaf(c3, bf2f_lo(v3.w), a[6]); a[7] = fmaf(c3, bf2f_hi(v3.w), a[7]);
    }
    for (; e < end; e++) {
        int s = csr[e];
        float c = dinv[s] * dd;
        uint4 v = h4[(size_t)s * 16 + t];
        a[0] = fmaf(c, bf2f_lo(v.x), a[0]); a[1] = fmaf(c, bf2f_hi(v.x), a[1]);
        a[2] = fmaf(c, bf2f_lo(v.y), a[2]); a[3] = fmaf(c, bf2f_hi(v.y), a[3]);
        a[4] = fmaf(c, bf2f_lo(v.z), a[4]); a[5] = fmaf(c, bf2f_hi(v.z), a[5]);
        a[6] = fmaf(c, bf2f_lo(v.w), a[6]); a[7] = fmaf(c, bf2f_hi(v.w), a[7]);
    }

    if (valid) {  // self-loop: coef = dinv^2
        float sc = dd * dd;
        uint4 v = h4[(size_t)node * 16 + t];
        a[0] = fmaf(sc, bf2f_lo(v.x), a[0]); a[1] = fmaf(sc, bf2f_hi(v.x), a[1]);
        a[2] = fmaf(sc, bf2f_lo(v.y), a[2]); a[3] = fmaf(sc, bf2f_hi(v.y), a[3]);
        a[4] = fmaf(sc, bf2f_lo(v.z), a[4]); a[5] = fmaf(sc, bf2f_hi(v.z), a[5]);
        a[6] = fmaf(sc, bf2f_lo(v.w), a[6]); a[7] = fmaf(sc, bf2f_hi(v.w), a[7]);
    }

    float4 b0 = ((const float4*)bias)[t * 2];
    float4 b1 = ((const float4*)bias)[t * 2 + 1];
    float r0 = fmaxf(a[0] + b0.x, 0.f), r1 = fmaxf(a[1] + b0.y, 0.f);
    float r2 = fmaxf(a[2] + b0.z, 0.f), r3 = fmaxf(a[3] + b0.w, 0.f);
    float r4 = fmaxf(a[4] + b1.x, 0.f), r5 = fmaxf(a[5] + b1.y, 0.f);
    float r6 = fmaxf(a[6] + b1.z, 0.f), r7 = fmaxf(a[7] + b1.w, 0.f);

    if (valid) {
        uint4 o;
        o.x = (unsigned int)f2bf(r0) | ((unsigned int)f2bf(r1) << 16);
        o.y = (unsigned int)f2bf(r2) | ((unsigned int)f2bf(r3) << 16);
        o.z = (unsigned int)f2bf(r4) | ((unsigned int)f2bf(r5) << 16);
        o.w = (unsigned int)f2bf(r6) | ((unsigned int)f2bf(r7) << 16);
        ((uint4*)out)[(size_t)node * 16 + t] = o;
    } else {
        r0 = r1 = r2 = r3 = r4 = r5 = r6 = r7 = 0.f;
    }

    if (threadIdx.x < 128) {
        ssum[threadIdx.x] = 0.f;
        ssq[threadIdx.x] = 0.f;
    }
    __syncthreads();
    float rr[8] = {r0, r1, r2, r3, r4, r5, r6, r7};
#pragma unroll
    for (int i = 0; i < 8; i++) {
        float sv = rr[i];
        float sq = sv * sv;
        sv += __shfl_xor(sv, 16); sq += __shfl_xor(sq, 16);
        sv += __shfl_xor(sv, 32); sq += __shfl_xor(sq, 32);
        if ((threadIdx.x & 63) < 16) {  // group 0 of each wave
            atomicAdd(&ssum[t * 8 + i], sv);
            atomicAdd(&ssq[t * 8 + i], sq);
        }
    }
    __syncthreads();
    if (threadIdx.x < 128) {
        atomicAdd(&gsum[threadIdx.x], ssum[threadIdx.x]);
        atomicAdd(&gsumsq[threadIdx.x], ssq[threadIdx.x]);
    }
}

// ---------------- BN finalize: scale/shift from stats; init bcP ----------------
__global__ void bn_finalize(const float* __restrict__ gsum, const float* __restrict__ gsumsq,
                            const float* __restrict__ gamma, const float* __restrict__ beta,
                            const float* __restrict__ bc, float* __restrict__ scale,
                            float* __restrict__ shift, float* __restrict__ bcP, float invN) {
    int j = threadIdx.x;  // 128
    float mu = gsum[j] * invN;
    float var = gsumsq[j] * invN - mu * mu;
    float sc = gamma[j] * rsqrtf(var + 1e-5f);
    scale[j] = sc;
    shift[j] = beta[j] - mu * sc;
    bcP[j] = bc[j];
}

// ---------------- fold BN into Wc (parallel): WcT[j][k] = bf16(scale_k*Wc[k][j]); bcP += shift@Wc ----------------
__global__ __launch_bounds__(256) void wcfold(const float* __restrict__ Wc,
                                              const float* __restrict__ scale,
                                              const float* __restrict__ shift,
                                              unsigned short* __restrict__ WcT,
                                              float* __restrict__ bcP) {
    __shared__ float scS[128], shS[128];
    if (threadIdx.x < 128) {
        scS[threadIdx.x] = scale[threadIdx.x];
        shS[threadIdx.x] = shift[threadIdx.x];
    }
    __syncthreads();
    int idx = blockIdx.x * 256 + threadIdx.x;  // 16384; j inner -> coalesced Wc reads
    int j = idx & 127, k = idx >> 7;
    float w = Wc[k * 128 + j];
    WcT[j * 128 + k] = f2bf(scS[k] * w);
    atomicAdd(&bcP[j], shS[k] * w);
}

// ---------------- host ----------------

extern "C" void kernel_launch(void* const* d_in, const int* in_sizes, int n_in,
                              void* d_out, int out_size, void* d_ws, size_t ws_size,
                              hipStream_t stream) {
    const float* x = (const float*)d_in[0];
    const int* ei = (const int*)d_in[1];
    const float* W1 = (const float*)d_in[2];
    const float* b1 = (const float*)d_in[3];
    const float* W2 = (const float*)d_in[4];
    const float* b2 = (const float*)d_in[5];
    const float* W3 = (const float*)d_in[6];
    const float* b3 = (const float*)d_in[7];
    const float* gamma = (const float*)d_in[8];
    const float* beta = (const float*)d_in[9];
    const float* Wc = (const float*)d_in[10];
    const float* bc = (const float*)d_in[11];
    const float* Wr = (const float*)d_in[12];
    const float* br = (const float*)d_in[13];
    float* out = (float*)d_out;

    const int N = in_sizes[0] / DHC;
    const int E = in_sizes[1] / 2;
    const int* srcIdx = ei;
    const int* dstIdx = ei + E;
    const int NB = (N + BSIZE - 1) >> BSHIFT;

    char* w = (char*)d_ws;
    size_t off = 0;
    auto alloc = [&](size_t bytes) -> void* {
        void* p = w + off;
        off += (bytes + 255) & ~(size_t)255;
        return p;
    };
    unsigned short* bufA = (unsigned short*)alloc((size_t)N * DHC * 2);
    unsigned short* bufB = (unsigned short*)alloc((size_t)N * DHC * 2);
    unsigned int* ebuf = (unsigned int*)alloc((size_t)E * 4);
    int* csr_src = (int*)alloc((size_t)E * 4);
    int* row_ptr = (int*)alloc((size_t)(N + 1) * 4);
    float* dinv = (float*)alloc((size_t)N * 4);
    // zeroed region: bcount[512] ++ stats[256] — one memset
    int* bcount = (int*)alloc(512 * 4 + 256 * 4);
    float* stats = (float*)(bcount + 512);
    float* gsum = stats;
    float* gsumsq = stats + 128;
    int* bbase = (int*)alloc(512 * 4);
    int* bcur = (int*)alloc(512 * 4);
    unsigned short* WTall = (unsigned short*)alloc((size_t)3 * 16384 * 2);
    unsigned short* WT1 = WTall;
    unsigned short* WT2 = WTall + 16384;
    unsigned short* WT3 = WTall + 32768;
    unsigned short* WcT = (unsigned short*)alloc(16384 * 2);
    float* scale = (float*)alloc(128 * 4);
    float* shift = (float*)alloc(128 * 4);
    float* bcP = (float*)alloc(128 * 4);
    (void)ws_size; (void)n_in; (void)out_size;

    hipMemsetAsync(bcount, 0, 512 * 4 + 256 * 4, stream);

    const int EB = (E + 4095) / 4096;
    bucket_hist<<<EB, 256, 0, stream>>>(dstIdx, bcount, E);
    bucket_scan<<<1, 512, 0, stream>>>(bcount, bbase, bcur, row_ptr, NB, N, E);
    bucket_scatter<<<EB, 256, 0, stream>>>(srcIdx, dstIdx, bcur, ebuf, E);
    bucket_build<<<NB, 256, 0, stream>>>(ebuf, bbase, row_ptr, csr_src, dinv, N);

    wconv3_k<<<192, 256, 0, stream>>>(W1, W2, W3, WTall);

    const int gemmBlocks = (N + 127) / 128;
    const int aggBlocks = (N + 15) / 16;

    // layer 1 (A = x fp32, converted in-flight)
    gemm_k<0, 1><<<gemmBlocks, 256, 0, stream>>>(x, WT1, nullptr, bufB, nullptr, nullptr, nullptr, N);
    agg_k<<<aggBlocks, 256, 0, stream>>>(bufB, csr_src, row_ptr, dinv, b1, bufA, N);
    // layer 2
    gemm_k<0, 0><<<gemmBlocks, 256, 0, stream>>>(bufA, WT2, nullptr, bufB, nullptr, nullptr, nullptr, N);
    agg_k<<<aggBlocks, 256, 0, stream>>>(bufB, csr_src, row_ptr, dinv, b2, bufA, N);
    // layer 3 (+ fused BN stats)
    gemm_k<0, 0><<<gemmBlocks, 256, 0, stream>>>(bufA, WT3, nullptr, bufB, nullptr, nullptr, nullptr, N);
    agg_stats_k<<<aggBlocks, 256, 0, stream>>>(bufB, csr_src, row_ptr, dinv, b3, bufA, gsum, gsumsq, N);

    // BN fold + classifier GEMM fused with output projection
    bn_finalize<<<1, 128, 0, stream>>>(gsum, gsumsq, gamma, beta, bc, scale, shift, bcP, 1.0f / (float)N);
    wcfold<<<64, 256, 0, stream>>>(Wc, scale, shift, WcT, bcP);
    gemm_k<2, 0><<<gemmBlocks, 256, 0, stream>>>(bufA, WcT, bcP, nullptr, out, Wr, br, N);
}

// Round 13
// 449.306 us; speedup vs baseline: 1.3426x; 1.2042x over previous
//
#include <hip/hip_runtime.h>

#define DHC 128
#define BSHIFT 8
#define BSIZE 256  // dst nodes per bucket

typedef __attribute__((ext_vector_type(8))) __bf16 bf16x8;
typedef __attribute__((ext_vector_type(8))) unsigned short ushort8;
typedef __attribute__((ext_vector_type(4))) float floatx4;

__device__ inline unsigned short f2bf(float f) {
    unsigned int u = __float_as_uint(f);
    return (unsigned short)((u + 0x7FFFu + ((u >> 16) & 1u)) >> 16);
}
__device__ inline float bf2f_lo(unsigned int v) { return __uint_as_float(v << 16); }
__device__ inline float bf2f_hi(unsigned int v) { return __uint_as_float(v & 0xFFFF0000u); }

// ---------------- graph prep: bucket sort by dst>>8, then per-bucket CSR ----------------

__global__ __launch_bounds__(256) void bucket_hist(const int* __restrict__ dst,
                                                   int* __restrict__ bcount, int e) {
    __shared__ int h[512];
    for (int i = threadIdx.x; i < 512; i += 256) h[i] = 0;
    __syncthreads();
    int base = blockIdx.x * 4096 + threadIdx.x;
#pragma unroll
    for (int j = 0; j < 16; j++) {
        int i = base + j * 256;
        if (i < e) atomicAdd(&h[dst[i] >> BSHIFT], 1);
    }
    __syncthreads();
    for (int i = threadIdx.x; i < 512; i += 256)
        if (h[i]) atomicAdd(&bcount[i], h[i]);
}

__global__ void bucket_scan(const int* __restrict__ bcount, int* __restrict__ bbase,
                            int* __restrict__ bcur, int* __restrict__ row_ptr,
                            int nb, int n, int e) {
    __shared__ int s[512];
    int t = threadIdx.x;
    s[t] = (t < nb) ? bcount[t] : 0;
    __syncthreads();
    for (int off = 1; off < 512; off <<= 1) {
        int add = (t >= off) ? s[t - off] : 0;
        __syncthreads();
        s[t] += add;
        __syncthreads();
    }
    if (t < nb) {
        int ex = (t == 0) ? 0 : s[t - 1];
        bbase[t] = ex;
        bcur[t] = ex;
    }
    if (t == 0) {
        bbase[nb] = e;
        row_ptr[n] = e;
    }
}

// scatter edges into bucket regions; packed entry = src | (dst_local << 20)
__global__ __launch_bounds__(256) void bucket_scatter(const int* __restrict__ src,
                                                      const int* __restrict__ dst,
                                                      int* __restrict__ bcur,
                                                      unsigned int* __restrict__ ebuf, int e) {
    __shared__ int h[512];
    __shared__ int rsv[512];
    for (int i = threadIdx.x; i < 512; i += 256) h[i] = 0;
    __syncthreads();
    int base = blockIdx.x * 4096 + threadIdx.x;
    int sreg[16], dreg[16];
#pragma unroll
    for (int j = 0; j < 16; j++) {
        int i = base + j * 256;
        if (i < e) {
            sreg[j] = src[i];
            dreg[j] = dst[i];
            atomicAdd(&h[dreg[j] >> BSHIFT], 1);
        } else {
            dreg[j] = -1;
        }
    }
    __syncthreads();
    for (int i = threadIdx.x; i < 512; i += 256) {
        int c = h[i];
        rsv[i] = c ? atomicAdd(&bcur[i], c) : 0;
        h[i] = 0;
    }
    __syncthreads();
#pragma unroll
    for (int j = 0; j < 16; j++) {
        if (dreg[j] >= 0) {
            int b = dreg[j] >> BSHIFT;
            int pos = rsv[b] + atomicAdd(&h[b], 1);
            ebuf[pos] = (unsigned int)sreg[j] | ((unsigned int)(dreg[j] & (BSIZE - 1)) << 20);
        }
    }
}

// one block per bucket: local deg, local scan -> row_ptr, dinv, csr_src
__global__ __launch_bounds__(256) void bucket_build(const unsigned int* __restrict__ ebuf,
                                                    const int* __restrict__ bbase,
                                                    int* __restrict__ row_ptr,
                                                    int* __restrict__ csr_src,
                                                    float* __restrict__ dinv, int n) {
    __shared__ int ldeg[256];
    __shared__ int lcur[256];
    int b = blockIdx.x;
    int t = threadIdx.x;
    int beg = bbase[b], end = bbase[b + 1];
    ldeg[t] = 0;
    __syncthreads();
    for (int i = beg + t; i < end; i += 256) atomicAdd(&ldeg[ebuf[i] >> 20], 1);
    __syncthreads();
    int deg = ldeg[t];
    lcur[t] = deg;
    __syncthreads();
    for (int off = 1; off < 256; off <<= 1) {
        int add = (t >= off) ? lcur[t - off] : 0;
        __syncthreads();
        lcur[t] += add;
        __syncthreads();
    }
    int rp = beg + lcur[t] - deg;  // exclusive
    int node = (b << BSHIFT) + t;
    if (node < n) {
        row_ptr[node] = rp;
        dinv[node] = rsqrtf((float)(deg + 1));
    }
    __syncthreads();
    lcur[t] = rp;
    __syncthreads();
    for (int i = beg + t; i < end; i += 256) {
        unsigned int p = ebuf[i];
        int pos = atomicAdd(&lcur[p >> 20], 1);
        csr_src[pos] = (int)(p & 0xFFFFFu);
    }
}

// ---------------- weight convert: 3x W[128k][128n] fp32 -> WT[n][k] bf16 ----------------
__global__ void wconv3_k(const float* __restrict__ W1, const float* __restrict__ W2,
                         const float* __restrict__ W3, unsigned short* __restrict__ WTall) {
    int idx = blockIdx.x * 256 + threadIdx.x;  // 3*16384
    int wsel = idx >> 14;
    int i = idx & 16383;
    int nn = i >> 7, k = i & 127;
    const float* W = (wsel == 0) ? W1 : (wsel == 1) ? W2 : W3;
    WTall[idx] = f2bf(W[k * 128 + nn]);
}

// ---------------- MFMA bf16 GEMM: out = A[N,128] @ W, B staged in LDS ----------------
template <int MODE, int AF32>
__global__ __launch_bounds__(256, 4) void gemm_k(const void* __restrict__ Avoid,
                                                 const unsigned short* __restrict__ WT,
                                                 const float* __restrict__ bias,
                                                 unsigned short* __restrict__ outB,
                                                 float* __restrict__ outF,
                                                 const float* __restrict__ Wr,
                                                 const float* __restrict__ br, int n) {
    __shared__ unsigned short Ws[32 * 512];
    {
        for (int c = threadIdx.x; c < 2048; c += 256) {
            int f = c >> 6;
            int l = c & 63;
            int ks = f >> 3, ct = f & 7;
            int nn = ct * 16 + (l & 15);
            int kb = ks * 32 + (l >> 4) * 8;
            *(uint4*)(&Ws[c * 8]) = *(const uint4*)(&WT[nn * 128 + kb]);
        }
    }
    __syncthreads();
    const int wave = threadIdx.x >> 6;
    const int lane = threadIdx.x & 63;
    const int rowbase = blockIdx.x * 128 + wave * 32;
    const int m = lane & 15;
    const int kq = lane >> 4;  // 0..3

    floatx4 acc[2][8];
#pragma unroll
    for (int rt = 0; rt < 2; rt++)
#pragma unroll
        for (int ct = 0; ct < 8; ct++) acc[rt][ct] = (floatx4){0.f, 0.f, 0.f, 0.f};

    const int r0 = min(rowbase + m, n - 1);
    const int r1 = min(rowbase + 16 + m, n - 1);

#pragma unroll
    for (int ks = 0; ks < 4; ks++) {
        const int kb = ks * 32 + kq * 8;
        bf16x8 a0, a1;
        if (AF32) {
            const float* Af = (const float*)Avoid;
            float4 f00 = *(const float4*)(Af + (size_t)r0 * 128 + kb);
            float4 f01 = *(const float4*)(Af + (size_t)r0 * 128 + kb + 4);
            float4 f10 = *(const float4*)(Af + (size_t)r1 * 128 + kb);
            float4 f11 = *(const float4*)(Af + (size_t)r1 * 128 + kb + 4);
            ushort8 u0, u1;
            u0[0] = f2bf(f00.x); u0[1] = f2bf(f00.y); u0[2] = f2bf(f00.z); u0[3] = f2bf(f00.w);
            u0[4] = f2bf(f01.x); u0[5] = f2bf(f01.y); u0[6] = f2bf(f01.z); u0[7] = f2bf(f01.w);
            u1[0] = f2bf(f10.x); u1[1] = f2bf(f10.y); u1[2] = f2bf(f10.z); u1[3] = f2bf(f10.w);
            u1[4] = f2bf(f11.x); u1[5] = f2bf(f11.y); u1[6] = f2bf(f11.z); u1[7] = f2bf(f11.w);
            a0 = __builtin_bit_cast(bf16x8, u0);
            a1 = __builtin_bit_cast(bf16x8, u1);
        } else {
            const unsigned short* Ab = (const unsigned short*)Avoid;
            a0 = __builtin_bit_cast(bf16x8, *(const ushort8*)(Ab + (size_t)r0 * 128 + kb));
            a1 = __builtin_bit_cast(bf16x8, *(const ushort8*)(Ab + (size_t)r1 * 128 + kb));
        }
#pragma unroll
        for (int ct = 0; ct < 8; ct++) {
            bf16x8 bfr = __builtin_bit_cast(bf16x8,
                *(const ushort8*)(&Ws[(ks * 8 + ct) * 512 + lane * 8]));
            acc[0][ct] = __builtin_amdgcn_mfma_f32_16x16x32_bf16(a0, bfr, acc[0][ct], 0, 0, 0);
            acc[1][ct] = __builtin_amdgcn_mfma_f32_16x16x32_bf16(a1, bfr, acc[1][ct], 0, 0, 0);
        }
    }

    if (MODE == 0) {
#pragma unroll
        for (int rt = 0; rt < 2; rt++) {
#pragma unroll
            for (int ct = 0; ct < 8; ct++) {
                int col = ct * 16 + m;
#pragma unroll
                for (int i = 0; i < 4; i++) {
                    int r = rowbase + rt * 16 + kq * 4 + i;
                    if (r < n) outB[(size_t)r * 128 + col] = f2bf(acc[rt][ct][i]);
                }
            }
        }
    } else {
        float bcv[8], wr0[8], wr1[8];
#pragma unroll
        for (int ct = 0; ct < 8; ct++) {
            int col = ct * 16 + m;
            bcv[ct] = bias[col];
            float2 wv = ((const float2*)Wr)[col];
            wr0[ct] = wv.x;
            wr1[ct] = wv.y;
        }
        float br0 = br[0], br1 = br[1];
#pragma unroll
        for (int rt = 0; rt < 2; rt++) {
#pragma unroll
            for (int i = 0; i < 4; i++) {
                float p0 = 0.f, p1 = 0.f;
#pragma unroll
                for (int ct = 0; ct < 8; ct++) {
                    float v = fmaxf(acc[rt][ct][i] + bcv[ct], 0.f);
                    p0 = fmaf(v, wr0[ct], p0);
                    p1 = fmaf(v, wr1[ct], p1);
                }
#pragma unroll
                for (int mk = 1; mk < 16; mk <<= 1) {
                    p0 += __shfl_xor(p0, mk);
                    p1 += __shfl_xor(p1, mk);
                }
                int r = rowbase + rt * 16 + kq * 4 + i;
                if (m == 0 && r < n) ((float2*)outF)[r] = make_float2(p0 + br0, p1 + br1);
            }
        }
    }
}

// ---------------- CSR gather aggregation: 16 lanes/node, explicit 4-edge unroll ----------------
__global__ __launch_bounds__(256) void agg_k(const unsigned short* __restrict__ hW,
                                             const int* __restrict__ csr,
                                             const int* __restrict__ row_ptr,
                                             const float* __restrict__ dinv,
                                             const float* __restrict__ bias,
                                             unsigned short* __restrict__ out, int n) {
    int node = blockIdx.x * 16 + (threadIdx.x >> 4);
    int t = threadIdx.x & 15;
    if (node >= n) return;
    int beg = row_ptr[node], end = row_ptr[node + 1];
    float dd = dinv[node];
    const uint4* h4 = (const uint4*)hW;
    float a[8];
#pragma unroll
    for (int i = 0; i < 8; i++) a[i] = 0.f;

    int e = beg;
    for (; e + 3 < end; e += 4) {
        int s0 = csr[e + 0], s1 = csr[e + 1], s2 = csr[e + 2], s3 = csr[e + 3];
        float c0 = dinv[s0] * dd, c1 = dinv[s1] * dd, c2 = dinv[s2] * dd, c3 = dinv[s3] * dd;
        uint4 v0 = h4[(size_t)s0 * 16 + t];
        uint4 v1 = h4[(size_t)s1 * 16 + t];
        uint4 v2 = h4[(size_t)s2 * 16 + t];
        uint4 v3 = h4[(size_t)s3 * 16 + t];
        a[0] = fmaf(c0, bf2f_lo(v0.x), a[0]); a[1] = fmaf(c0, bf2f_hi(v0.x), a[1]);
        a[2] = fmaf(c0, bf2f_lo(v0.y), a[2]); a[3] = fmaf(c0, bf2f_hi(v0.y), a[3]);
        a[4] = fmaf(c0, bf2f_lo(v0.z), a[4]); a[5] = fmaf(c0, bf2f_hi(v0.z), a[5]);
        a[6] = fmaf(c0, bf2f_lo(v0.w), a[6]); a[7] = fmaf(c0, bf2f_hi(v0.w), a[7]);
        a[0] = fmaf(c1, bf2f_lo(v1.x), a[0]); a[1] = fmaf(c1, bf2f_hi(v1.x), a[1]);
        a[2] = fmaf(c1, bf2f_lo(v1.y), a[2]); a[3] = fmaf(c1, bf2f_hi(v1.y), a[3]);
        a[4] = fmaf(c1, bf2f_lo(v1.z), a[4]); a[5] = fmaf(c1, bf2f_hi(v1.z), a[5]);
        a[6] = fmaf(c1, bf2f_lo(v1.w), a[6]); a[7] = fmaf(c1, bf2f_hi(v1.w), a[7]);
        a[0] = fmaf(c2, bf2f_lo(v2.x), a[0]); a[1] = fmaf(c2, bf2f_hi(v2.x), a[1]);
        a[2] = fmaf(c2, bf2f_lo(v2.y), a[2]); a[3] = fmaf(c2, bf2f_hi(v2.y), a[3]);
        a[4] = fmaf(c2, bf2f_lo(v2.z), a[4]); a[5] = fmaf(c2, bf2f_hi(v2.z), a[5]);
        a[6] = fmaf(c2, bf2f_lo(v2.w), a[6]); a[7] = fmaf(c2, bf2f_hi(v2.w), a[7]);
        a[0] = fmaf(c3, bf2f_lo(v3.x), a[0]); a[1] = fmaf(c3, bf2f_hi(v3.x), a[1]);
        a[2] = fmaf(c3, bf2f_lo(v3.y), a[2]); a[3] = fmaf(c3, bf2f_hi(v3.y), a[3]);
        a[4] = fmaf(c3, bf2f_lo(v3.z), a[4]); a[5] = fmaf(c3, bf2f_hi(v3.z), a[5]);
        a[6] = fmaf(c3, bf2f_lo(v3.w), a[6]); a[7] = fmaf(c3, bf2f_hi(v3.w), a[7]);
    }
    for (; e < end; e++) {
        int s = csr[e];
        float c = dinv[s] * dd;
        uint4 v = h4[(size_t)s * 16 + t];
        a[0] = fmaf(c, bf2f_lo(v.x), a[0]); a[1] = fmaf(c, bf2f_hi(v.x), a[1]);
        a[2] = fmaf(c, bf2f_lo(v.y), a[2]); a[3] = fmaf(c, bf2f_hi(v.y), a[3]);
        a[4] = fmaf(c, bf2f_lo(v.z), a[4]); a[5] = fmaf(c, bf2f_hi(v.z), a[5]);
        a[6] = fmaf(c, bf2f_lo(v.w), a[6]); a[7] = fmaf(c, bf2f_hi(v.w), a[7]);
    }

    // self-loop: coef = dinv^2
    {
        float sc = dd * dd;
        uint4 v = h4[(size_t)node * 16 + t];
        a[0] = fmaf(sc, bf2f_lo(v.x), a[0]); a[1] = fmaf(sc, bf2f_hi(v.x), a[1]);
        a[2] = fmaf(sc, bf2f_lo(v.y), a[2]); a[3] = fmaf(sc, bf2f_hi(v.y), a[3]);
        a[4] = fmaf(sc, bf2f_lo(v.z), a[4]); a[5] = fmaf(sc, bf2f_hi(v.z), a[5]);
        a[6] = fmaf(sc, bf2f_lo(v.w), a[6]); a[7] = fmaf(sc, bf2f_hi(v.w), a[7]);
    }
    float4 b0 = ((const float4*)bias)[t * 2];
    float4 b1 = ((const float4*)bias)[t * 2 + 1];
    uint4 o;
    o.x = (unsigned int)f2bf(fmaxf(a[0] + b0.x, 0.f)) |
          ((unsigned int)f2bf(fmaxf(a[1] + b0.y, 0.f)) << 16);
    o.y = (unsigned int)f2bf(fmaxf(a[2] + b0.z, 0.f)) |
          ((unsigned int)f2bf(fmaxf(a[3] + b0.w, 0.f)) << 16);
    o.z = (unsigned int)f2bf(fmaxf(a[4] + b1.x, 0.f)) |
          ((unsigned int)f2bf(fmaxf(a[5] + b1.y, 0.f)) << 16);
    o.w = (unsigned int)f2bf(fmaxf(a[6] + b1.z, 0.f)) |
          ((unsigned int)f2bf(fmaxf(a[7] + b1.w, 0.f)) << 16);
    ((uint4*)out)[(size_t)node * 16 + t] = o;
}

// ---------------- BN stats (per-channel sum / sumsq) over bf16 h — 256 blocks, 65k atomics ----------------
__global__ __launch_bounds__(256) void bn_stats(const unsigned short* __restrict__ h,
                                                float* __restrict__ gsum,
                                                float* __restrict__ gsumsq, int n) {
    __shared__ float red[4][256];
    int l = threadIdx.x & 63;
    int rs = threadIdx.x >> 6;
    float s0 = 0.f, s1 = 0.f, q0 = 0.f, q1 = 0.f;
    for (int r = blockIdx.x * 4 + rs; r < n; r += gridDim.x * 4) {
        unsigned int v = *(const unsigned int*)(h + (size_t)r * 128 + l * 2);
        float a = bf2f_lo(v), b = bf2f_hi(v);
        s0 += a;
        s1 += b;
        q0 = fmaf(a, a, q0);
        q1 = fmaf(b, b, q1);
    }
    red[0][threadIdx.x] = s0;
    red[1][threadIdx.x] = s1;
    red[2][threadIdx.x] = q0;
    red[3][threadIdx.x] = q1;
    __syncthreads();
    if (threadIdx.x < 64) {
        float S0 = 0.f, S1 = 0.f, Q0 = 0.f, Q1 = 0.f;
#pragma unroll
        for (int j = 0; j < 4; j++) {
            S0 += red[0][j * 64 + l];
            S1 += red[1][j * 64 + l];
            Q0 += red[2][j * 64 + l];
            Q1 += red[3][j * 64 + l];
        }
        atomicAdd(&gsum[2 * l + 0], S0);
        atomicAdd(&gsum[2 * l + 1], S1);
        atomicAdd(&gsumsq[2 * l + 0], Q0);
        atomicAdd(&gsumsq[2 * l + 1], Q1);
    }
}

// ---------------- BN finalize: scale/shift from stats; init bcP ----------------
__global__ void bn_finalize(const float* __restrict__ gsum, const float* __restrict__ gsumsq,
                            const float* __restrict__ gamma, const float* __restrict__ beta,
                            const float* __restrict__ bc, float* __restrict__ scale,
                            float* __restrict__ shift, float* __restrict__ bcP, float invN) {
    int j = threadIdx.x;  // 128
    float mu = gsum[j] * invN;
    float var = gsumsq[j] * invN - mu * mu;
    float sc = gamma[j] * rsqrtf(var + 1e-5f);
    scale[j] = sc;
    shift[j] = beta[j] - mu * sc;
    bcP[j] = bc[j];
}

// ---------------- fold BN into Wc (parallel): WcT[j][k] = bf16(scale_k*Wc[k][j]); bcP += shift@Wc ----------------
__global__ __launch_bounds__(256) void wcfold(const float* __restrict__ Wc,
                                              const float* __restrict__ scale,
                                              const float* __restrict__ shift,
                                              unsigned short* __restrict__ WcT,
                                              float* __restrict__ bcP) {
    __shared__ float scS[128], shS[128];
    if (threadIdx.x < 128) {
        scS[threadIdx.x] = scale[threadIdx.x];
        shS[threadIdx.x] = shift[threadIdx.x];
    }
    __syncthreads();
    int idx = blockIdx.x * 256 + threadIdx.x;  // 16384; j inner -> coalesced Wc reads
    int j = idx & 127, k = idx >> 7;
    float w = Wc[k * 128 + j];
    WcT[j * 128 + k] = f2bf(scS[k] * w);
    atomicAdd(&bcP[j], shS[k] * w);
}

// ---------------- host ----------------

extern "C" void kernel_launch(void* const* d_in, const int* in_sizes, int n_in,
                              void* d_out, int out_size, void* d_ws, size_t ws_size,
                              hipStream_t stream) {
    const float* x = (const float*)d_in[0];
    const int* ei = (const int*)d_in[1];
    const float* W1 = (const float*)d_in[2];
    const float* b1 = (const float*)d_in[3];
    const float* W2 = (const float*)d_in[4];
    const float* b2 = (const float*)d_in[5];
    const float* W3 = (const float*)d_in[6];
    const float* b3 = (const float*)d_in[7];
    const float* gamma = (const float*)d_in[8];
    const float* beta = (const float*)d_in[9];
    const float* Wc = (const float*)d_in[10];
    const float* bc = (const float*)d_in[11];
    const float* Wr = (const float*)d_in[12];
    const float* br = (const float*)d_in[13];
    float* out = (float*)d_out;

    const int N = in_sizes[0] / DHC;
    const int E = in_sizes[1] / 2;
    const int* srcIdx = ei;
    const int* dstIdx = ei + E;
    const int NB = (N + BSIZE - 1) >> BSHIFT;

    char* w = (char*)d_ws;
    size_t off = 0;
    auto alloc = [&](size_t bytes) -> void* {
        void* p = w + off;
        off += (bytes + 255) & ~(size_t)255;
        return p;
    };
    unsigned short* bufA = (unsigned short*)alloc((size_t)N * DHC * 2);
    unsigned short* bufB = (unsigned short*)alloc((size_t)N * DHC * 2);
    unsigned int* ebuf = (unsigned int*)alloc((size_t)E * 4);
    int* csr_src = (int*)alloc((size_t)E * 4);
    int* row_ptr = (int*)alloc((size_t)(N + 1) * 4);
    float* dinv = (float*)alloc((size_t)N * 4);
    // zeroed region: bcount[512] ++ stats[256] — one memset
    int* bcount = (int*)alloc(512 * 4 + 256 * 4);
    float* stats = (float*)(bcount + 512);
    float* gsum = stats;
    float* gsumsq = stats + 128;
    int* bbase = (int*)alloc(512 * 4);
    int* bcur = (int*)alloc(512 * 4);
    unsigned short* WTall = (unsigned short*)alloc((size_t)3 * 16384 * 2);
    unsigned short* WT1 = WTall;
    unsigned short* WT2 = WTall + 16384;
    unsigned short* WT3 = WTall + 32768;
    unsigned short* WcT = (unsigned short*)alloc(16384 * 2);
    float* scale = (float*)alloc(128 * 4);
    float* shift = (float*)alloc(128 * 4);
    float* bcP = (float*)alloc(128 * 4);
    (void)ws_size; (void)n_in; (void)out_size;

    hipMemsetAsync(bcount, 0, 512 * 4 + 256 * 4, stream);

    const int EB = (E + 4095) / 4096;
    bucket_hist<<<EB, 256, 0, stream>>>(dstIdx, bcount, E);
    bucket_scan<<<1, 512, 0, stream>>>(bcount, bbase, bcur, row_ptr, NB, N, E);
    bucket_scatter<<<EB, 256, 0, stream>>>(srcIdx, dstIdx, bcur, ebuf, E);
    bucket_build<<<NB, 256, 0, stream>>>(ebuf, bbase, row_ptr, csr_src, dinv, N);

    wconv3_k<<<192, 256, 0, stream>>>(W1, W2, W3, WTall);

    const int gemmBlocks = (N + 127) / 128;
    const int aggBlocks = (N + 15) / 16;

    // layer 1 (A = x fp32, converted in-flight)
    gemm_k<0, 1><<<gemmBlocks, 256, 0, stream>>>(x, WT1, nullptr, bufB, nullptr, nullptr, nullptr, N);
    agg_k<<<aggBlocks, 256, 0, stream>>>(bufB, csr_src, row_ptr, dinv, b1, bufA, N);
    // layer 2
    gemm_k<0, 0><<<gemmBlocks, 256, 0, stream>>>(bufA, WT2, nullptr, bufB, nullptr, nullptr, nullptr, N);
    agg_k<<<aggBlocks, 256, 0, stream>>>(bufB, csr_src, row_ptr, dinv, b2, bufA, N);
    // layer 3
    gemm_k<0, 0><<<gemmBlocks, 256, 0, stream>>>(bufA, WT3, nullptr, bufB, nullptr, nullptr, nullptr, N);
    agg_k<<<aggBlocks, 256, 0, stream>>>(bufB, csr_src, row_ptr, dinv, b3, bufA, N);

    // batchnorm stats + fold + classifier GEMM fused with output projection
    bn_stats<<<256, 256, 0, stream>>>(bufA, gsum, gsumsq, N);
    bn_finalize<<<1, 128, 0, stream>>>(gsum, gsumsq, gamma, beta, bc, scale, shift, bcP, 1.0f / (float)N);
    wcfold<<<64, 256, 0, stream>>>(Wc, scale, shift, WcT, bcP);
    gemm_k<2, 0><<<gemmBlocks, 256, 0, stream>>>(bufA, WcT, bcP, nullptr, out, Wr, br, N);
}